// Round 13
// baseline (774.345 us; speedup 1.0000x reference)
//
#include <hip/hip_runtime.h>
#include <hip/hip_bf16.h>

#define NN 50000
#define NE 800000
#define INC 128
#define HID 64
#define OUTC 32
#define NREL 8
#define NG 64
#define SLOPE 0.2f
#define NB2 196          // dst buckets of 256 nodes
#define SCAP 6144        // sortpass LDS stage capacity (mean 4096, sd 64)
#define S_BLOCKS (NN / 16)   // 3125
#define ENC_BLOCKS 512
#define HISTO_BLOCKS ((NE + 2047) / 2048)   // 391

typedef unsigned int uint32;
typedef unsigned short ushort16;
typedef __attribute__((ext_vector_type(8))) short short8;
typedef __attribute__((ext_vector_type(4))) short short4v;
typedef __attribute__((ext_vector_type(4))) float float4v;
typedef __attribute__((ext_vector_type(4))) int int4v;

__device__ __forceinline__ float bf2f(ushort16 u) {
    union { uint32 i; float f; } v; v.i = ((uint32)u) << 16; return v.f;
}
__device__ __forceinline__ ushort16 f2bf(float f) {
    union { float f; uint32 i; } v; v.f = f;
    uint32 i = v.i;
    return (ushort16)((i + 0x7FFFu + ((i >> 16) & 1u)) >> 16);   // RNE
}

// =====================================================================
// prep: wqk for both layers + zero {bucketHist, bucket_cur, pooled}
// =====================================================================
__global__ __launch_bounds__(256) void prep_kernel(
    const float* __restrict__ w0, const float* __restrict__ q0, const float* __restrict__ k0,
    const float* __restrict__ w1, const float* __restrict__ q1, const float* __restrict__ k1,
    float* __restrict__ wqk0, float* __restrict__ wqk1,
    int* __restrict__ bucketHist, int* __restrict__ bucket_cur,
    float* __restrict__ pooled)
{
    int b = blockIdx.x, t = threadIdx.x;
    if (b < 32) {
        const float* w  = (b < 16) ? w0 : w1;
        const float* qv = (b < 16) ? q0 : q1;
        const float* kv = (b < 16) ? k0 : k1;
        float* out = (b < 16) ? wqk0 : wqk1;
        int j = b & 15;
        int r = j & 7;
        const float* vv = (j < 8) ? qv : kv;
        if (t < 64) {
            const float* wr = w + ((size_t)r * HID + t) * HID;
            float acc = 0.f;
            for (int o = 0; o < HID; ++o) acc += wr[o] * vv[o];
            out[j * HID + t] = acc;
        }
    } else {
        if (t < NB2) { bucketHist[t] = 0; bucket_cur[t] = 0; }
        #pragma unroll
        for (int i = 0; i < (NG * HID) / 256; ++i) pooled[i * 256 + t] = 0.f;
    }
}

// =====================================================================
// enchisto: blocks [0,512) = encoder MFMA GEMM; blocks [512,903) = histo.
// =====================================================================
__global__ __launch_bounds__(256) void enchisto_kernel(const float* __restrict__ x,
    const float* __restrict__ W, const float* __restrict__ bias,
    ushort16* __restrict__ hb,
    const int* __restrict__ dst, int* __restrict__ bucketHist)
{
    __shared__ float lds[4][16 * 65];
    __shared__ int lh[NB2];
    int tid = threadIdx.x;

    if (blockIdx.x >= ENC_BLOCKS) {
        // ---------------- histo body ----------------
        for (int i = tid; i < NB2; i += 256) lh[i] = 0;
        __syncthreads();
        int base = (blockIdx.x - ENC_BLOCKS) * 2048;
        for (int i = tid; i < 2048; i += 256) {
            int idx = base + i;
            if (idx < NE) atomicAdd(&lh[dst[idx] >> 8], 1);
        }
        __syncthreads();
        for (int i = tid; i < NB2; i += 256) if (lh[i]) atomicAdd(&bucketHist[i], lh[i]);
        return;
    }

    // ---------------- enc body ----------------
    int wv = tid >> 6, lane = tid & 63;
    int g = lane >> 4, lr = lane & 15;

    short8 bf[4][4];                       // [colTile][kChunk]
    for (int t = 0; t < 4; ++t)
        for (int kc = 0; kc < 4; ++kc) {
            short8 v;
            #pragma unroll
            for (int j = 0; j < 8; ++j) {
                int k = kc * 32 + g * 8 + j;
                v[j] = (short)f2bf(W[k * HID + t * 16 + lr]);
            }
            bf[t][kc] = v;
        }

    float* myl = lds[wv];

    for (int tile = blockIdx.x * 4 + wv; tile < NN / 16; tile += ENC_BLOCKS * 4) {
        int row0 = tile * 16;
        const float4v* xp = (const float4v*)(x + (size_t)(row0 + lr) * INC);
        short8 af[4];
        #pragma unroll
        for (int kc = 0; kc < 4; ++kc) {
            float4v u0 = xp[kc * 8 + g * 2];
            float4v u1 = xp[kc * 8 + g * 2 + 1];
            short8 v;
            v[0] = (short)f2bf(u0[0]); v[1] = (short)f2bf(u0[1]);
            v[2] = (short)f2bf(u0[2]); v[3] = (short)f2bf(u0[3]);
            v[4] = (short)f2bf(u1[0]); v[5] = (short)f2bf(u1[1]);
            v[6] = (short)f2bf(u1[2]); v[7] = (short)f2bf(u1[3]);
            af[kc] = v;
        }
        float4v acc[4];
        #pragma unroll
        for (int t = 0; t < 4; ++t) { float4v z = {0.f,0.f,0.f,0.f}; acc[t] = z; }
        #pragma unroll
        for (int t = 0; t < 4; ++t)
            #pragma unroll
            for (int kc = 0; kc < 4; ++kc)
                acc[t] = __builtin_amdgcn_mfma_f32_16x16x32_bf16(af[kc], bf[t][kc], acc[t], 0, 0, 0);

        #pragma unroll
        for (int t = 0; t < 4; ++t)
            #pragma unroll
            for (int i = 0; i < 4; ++i)
                myl[(4 * g + i) * 65 + t * 16 + lr] = acc[t][i];
        __asm volatile("s_waitcnt lgkmcnt(0)" ::: "memory");

        int row = lane >> 2, cg = lane & 3;
        const float* srcp = myl + row * 65 + cg * 16;
        uint32 p[8];
        #pragma unroll
        for (int j = 0; j < 8; ++j) {
            float v0 = srcp[2 * j]     + bias[cg * 16 + 2 * j];
            float v1 = srcp[2 * j + 1] + bias[cg * 16 + 2 * j + 1];
            p[j] = (uint32)f2bf(v0) | ((uint32)f2bf(v1) << 16);
        }
        int4v s0 = {(int)p[0], (int)p[1], (int)p[2], (int)p[3]};
        int4v s1 = {(int)p[4], (int)p[5], (int)p[6], (int)p[7]};
        int4v* op = (int4v*)(hb + (size_t)(row0 + row) * HID + cg * 16);
        op[0] = s0; op[1] = s1;
        __asm volatile("s_waitcnt lgkmcnt(0)" ::: "memory");
    }
}

// =====================================================================
// sh_kernel: fused s (scores) + hall (per-relation transform).
// Blocks [0, S_BLOCKS): sbuf[j][n] = h[n,:].wqk[j,:]
// Blocks [S_BLOCKS, S_BLOCKS+512*NREL): hall[r] = bf16(h @ w[r])
// =====================================================================
__global__ __launch_bounds__(256) void sh_kernel(const ushort16* __restrict__ hb,
    const float* __restrict__ wqk, const float* __restrict__ w,
    float* __restrict__ sbuf, ushort16* __restrict__ hall)
{
    __shared__ float lds4[4][16 * 65];     // hall part
    __shared__ float Ws[16 * 65];          // s part
    __shared__ short4v Hs[16][17];         // s part
    int tid = threadIdx.x;

    if (blockIdx.x < S_BLOCKS) {
        // ---------------- s body ----------------
        for (int i = tid; i < 16 * HID; i += 256) Ws[(i >> 6) * 65 + (i & 63)] = wqk[i];
        int n0 = blockIdx.x * 16;
        {
            int row = tid >> 4, ch = tid & 15;
            Hs[row][ch] = *(const short4v*)(hb + (size_t)(n0 + row) * HID + ch * 4);
        }
        __syncthreads();
        int j = tid & 15, nl = tid >> 4;
        short4v hreg[16];
        #pragma unroll
        for (int c = 0; c < 16; ++c) hreg[c] = Hs[nl][c];
        float acc = 0.f;
        #pragma unroll
        for (int c = 0; c < 16; ++c)
            #pragma unroll
            for (int u = 0; u < 4; ++u)
                acc += bf2f((ushort16)hreg[c][u]) * Ws[j * 65 + c * 4 + u];
        sbuf[(size_t)j * NN + n0 + nl] = acc;
        return;
    }

    // ---------------- hall body ----------------
    int b = blockIdx.x - S_BLOCKS;
    int r = b >> 9, xb = b & 511;
    int wv = tid >> 6, lane = tid & 63;
    int g = lane >> 4, lr = lane & 15;
    const float* wr = w + (size_t)r * HID * HID;

    short8 bfr[4][2];
    for (int t = 0; t < 4; ++t)
        for (int kc = 0; kc < 2; ++kc) {
            short8 v;
            #pragma unroll
            for (int j = 0; j < 8; ++j) {
                int k = kc * 32 + g * 8 + j;
                v[j] = (short)f2bf(wr[k * HID + t * 16 + lr]);
            }
            bfr[t][kc] = v;
        }

    float* myl = lds4[wv];
    ushort16* outr = hall + (size_t)r * NN * HID;

    for (int tile = xb * 4 + wv; tile < NN / 16; tile += 512 * 4) {
        int row0 = tile * 16;
        const short8* ap = (const short8*)(hb + (size_t)(row0 + lr) * HID);
        short8 a0 = ap[g];
        short8 a1 = ap[4 + g];
        float4v acc[4];
        #pragma unroll
        for (int t = 0; t < 4; ++t) { float4v z = {0.f,0.f,0.f,0.f}; acc[t] = z; }
        #pragma unroll
        for (int t = 0; t < 4; ++t) {
            acc[t] = __builtin_amdgcn_mfma_f32_16x16x32_bf16(a0, bfr[t][0], acc[t], 0, 0, 0);
            acc[t] = __builtin_amdgcn_mfma_f32_16x16x32_bf16(a1, bfr[t][1], acc[t], 0, 0, 0);
        }
        #pragma unroll
        for (int t = 0; t < 4; ++t)
            #pragma unroll
            for (int i = 0; i < 4; ++i)
                myl[(4 * g + i) * 65 + t * 16 + lr] = acc[t][i];
        __asm volatile("s_waitcnt lgkmcnt(0)" ::: "memory");

        int row = lane >> 2, cg = lane & 3;
        const float* srcp = myl + row * 65 + cg * 16;
        uint32 p[8];
        #pragma unroll
        for (int j = 0; j < 8; ++j)
            p[j] = (uint32)f2bf(srcp[2 * j]) | ((uint32)f2bf(srcp[2 * j + 1]) << 16);
        int4v s0 = {(int)p[0], (int)p[1], (int)p[2], (int)p[3]};
        int4v s1 = {(int)p[4], (int)p[5], (int)p[6], (int)p[7]};
        int4v* op = (int4v*)(outr + (size_t)(row0 + row) * HID + cg * 16);
        op[0] = s0; op[1] = s1;
        __asm volatile("s_waitcnt lgkmcnt(0)" ::: "memory");
    }
}

// =====================================================================
// binpass: bin edges into buckets. Computes the 196-bucket exclusive
// scan locally from bucketHist (replaces the scan196 dispatch).
// =====================================================================
__global__ __launch_bounds__(256) void binpass(const int* __restrict__ src,
    const int* __restrict__ dst, const int* __restrict__ et,
    const int* __restrict__ bucketHist,
    int* __restrict__ bucket_cur, uint32* __restrict__ ebin)
{
    __shared__ int ps[256], baseSh[NB2];
    __shared__ int lh[NB2], lbase[NB2], lcur[NB2];
    int t = threadIdx.x;

    // local exclusive scan of bucketHist
    int v = (t < NB2) ? bucketHist[t] : 0;
    ps[t] = v;
    __syncthreads();
    for (int off = 1; off < 256; off <<= 1) {
        int tv = (t >= off) ? ps[t - off] : 0;
        __syncthreads();
        ps[t] += tv;
        __syncthreads();
    }
    if (t < NB2) baseSh[t] = ps[t] - v;

    for (int i = t; i < NB2; i += 256) { lh[i] = 0; lcur[i] = 0; }
    __syncthreads();

    int base = blockIdx.x * 4096;
    uint32 rec[16]; int bkt[16];
    #pragma unroll
    for (int i = 0; i < 16; ++i) {
        int idx = base + i * 256 + t;
        bkt[i] = -1;
        if (idx < NE) {
            int s = src[idx], d = dst[idx], r = et[idx];
            rec[i] = (uint32)s | ((uint32)r << 16) | ((uint32)(d & 255) << 19);
            bkt[i] = d >> 8;
            atomicAdd(&lh[bkt[i]], 1);
        }
    }
    __syncthreads();
    for (int i = t; i < NB2; i += 256)
        if (lh[i]) lbase[i] = baseSh[i] + atomicAdd(&bucket_cur[i], lh[i]);
    __syncthreads();
    #pragma unroll
    for (int i = 0; i < 16; ++i) {
        if (bkt[i] >= 0) {
            int lpos = atomicAdd(&lcur[bkt[i]], 1);
            ebin[lbase[bkt[i]] + lpos] = rec[i];
        }
    }
}

// =====================================================================
// sortpass: per-bucket fine sort; computes bucket base locally from
// bucketHist scan. Writes rowptr.
// =====================================================================
__global__ __launch_bounds__(256) void sortpass(const uint32* __restrict__ ebin,
    const int* __restrict__ bucketHist, int* __restrict__ rowptr,
    uint32* __restrict__ edges_s)
{
    __shared__ uint32 stage[SCAP];
    __shared__ int cnt256[256], ps[256], cur[256];
    __shared__ int segSh[2];
    int b = blockIdx.x, t = threadIdx.x;

    // local scan for this bucket's segment
    int v = (t < NB2) ? bucketHist[t] : 0;
    ps[t] = v;
    __syncthreads();
    for (int off = 1; off < 256; off <<= 1) {
        int tv = (t >= off) ? ps[t - off] : 0;
        __syncthreads();
        ps[t] += tv;
        __syncthreads();
    }
    if (t == b) { segSh[0] = ps[t] - v; segSh[1] = ps[t]; }
    __syncthreads();
    int seg0 = segSh[0], seg1 = segSh[1];
    int cnt = seg1 - seg0;

    cnt256[t] = 0;
    __syncthreads();
    for (int i = t; i < cnt; i += 256) {
        uint32 rec = ebin[seg0 + i];
        atomicAdd(&cnt256[(rec >> 19) & 255], 1);
    }
    __syncthreads();
    int v2 = cnt256[t];
    ps[t] = v2;
    __syncthreads();
    for (int off = 1; off < 256; off <<= 1) {
        int tv = (t >= off) ? ps[t - off] : 0;
        __syncthreads();
        ps[t] += tv;
        __syncthreads();
    }
    int excl = ps[t] - v2;
    int node = (b << 8) + t;
    if (node < NN) rowptr[node] = seg0 + excl;
    if (b == NB2 - 1 && t == 0) rowptr[NN] = NE;
    cur[t] = excl;
    __syncthreads();
    for (int i = t; i < cnt; i += 256) {
        uint32 rec = ebin[seg0 + i];
        int lpos = atomicAdd(&cur[(rec >> 19) & 255], 1);
        if (lpos < SCAP) stage[lpos] = rec;
        else edges_s[seg0 + lpos] = rec;
    }
    __syncthreads();
    int lim = cnt < SCAP ? cnt : SCAP;
    for (int i = t; i < lim; i += 256) edges_s[seg0 + i] = stage[i];
}

// =====================================================================
// Fused per-dst softmax + aggregate + bias.
// One wave per node; 8 groups of 8 lanes; 2 edges in flight per group.
// do_relu==1: relu + bf16 write to out_bf (layer 0).
// do_relu==0: fused global_add_pool — atomicAdd into pooled[batch[d]] (layer 1).
// =====================================================================
__global__ __launch_bounds__(256) void agg_kernel(const int* __restrict__ rowptr,
    const uint32* __restrict__ edges, const float* __restrict__ sbuf,
    const ushort16* __restrict__ hall, const float* __restrict__ bias,
    ushort16* __restrict__ out_bf, const int* __restrict__ batch,
    float* __restrict__ pooled, int do_relu)
{
    int wv = threadIdx.x >> 6, lane = threadIdx.x & 63;
    int d = blockIdx.x * 4 + wv;
    if (d >= NN) return;
    int row0 = rowptr[d];
    int deg = rowptr[d + 1] - row0;
    int g = lane >> 3, cl = lane & 7;

    float myq = (lane < 8) ? sbuf[lane * NN + d] : 0.f;

    float acc[8];
    #pragma unroll
    for (int u = 0; u < 8; ++u) acc[u] = 0.f;
    float ssum = 0.f;

    for (int base = 0; base < deg; base += 16) {
        int j0 = base + g, j1 = j0 + 8;
        bool v0 = j0 < deg, v1 = j1 < deg;
        uint32 pk0 = v0 ? edges[row0 + j0] : 0u;
        uint32 pk1 = v1 ? edges[row0 + j1] : 0u;
        int s0 = (int)(pk0 & 0xFFFFu), r0 = (int)((pk0 >> 16) & 7u);
        int s1 = (int)(pk1 & 0xFFFFu), r1 = (int)((pk1 >> 16) & 7u);
        float sc0 = sbuf[(8 + r0) * NN + s0];
        float sc1 = sbuf[(8 + r1) * NN + s1];
        short8 hv0 = *(const short8*)(hall + ((size_t)r0 * NN + s0) * HID + cl * 8);
        short8 hv1 = *(const short8*)(hall + ((size_t)r1 * NN + s1) * HID + cl * 8);
        float a0 = __shfl(myq, r0) + sc0; a0 = (a0 > 0.f) ? a0 : SLOPE * a0;
        float a1 = __shfl(myq, r1) + sc1; a1 = (a1 > 0.f) ? a1 : SLOPE * a1;
        float ex0 = v0 ? __expf(a0) : 0.f;
        float ex1 = v1 ? __expf(a1) : 0.f;
        ssum += ex0 + ex1;
        #pragma unroll
        for (int u = 0; u < 8; ++u)
            acc[u] += ex0 * bf2f((ushort16)hv0[u]) + ex1 * bf2f((ushort16)hv1[u]);
    }

    #pragma unroll
    for (int o = 8; o < 64; o <<= 1) {
        ssum += __shfl_xor(ssum, o);
        #pragma unroll
        for (int u = 0; u < 8; ++u) acc[u] += __shfl_xor(acc[u], o);
    }

    if (lane < 8) {
        float inv = 1.f / fmaxf(ssum, 1e-16f);
        float o_[8];
        #pragma unroll
        for (int u = 0; u < 8; ++u) o_[u] = acc[u] * inv + bias[lane * 8 + u];
        if (do_relu) {
            uint32 p[4];
            #pragma unroll
            for (int u = 0; u < 4; ++u) {
                float v0 = fmaxf(o_[2 * u], 0.f);
                float v1 = fmaxf(o_[2 * u + 1], 0.f);
                p[u] = (uint32)f2bf(v0) | ((uint32)f2bf(v1) << 16);
            }
            int4v pk4 = {(int)p[0], (int)p[1], (int)p[2], (int)p[3]};
            *(int4v*)(out_bf + (size_t)d * HID + lane * 8) = pk4;
        } else {
            int gi = batch[d];
            float* pp = pooled + (size_t)gi * HID + lane * 8;
            #pragma unroll
            for (int u = 0; u < 8; ++u) atomicAdd(&pp[u], o_[u]);
        }
    }
}

// ---------------- head ----------------
__global__ __launch_bounds__(256) void head_kernel(const float* __restrict__ pooled,
    const float* __restrict__ linW, const float* __restrict__ linb,
    const float* __restrict__ clfW, const float* __restrict__ clfb,
    float* __restrict__ out)
{
    __shared__ float z[NG * HID];
    __shared__ float p[NG * HID];
    int tid = threadIdx.x;
    for (int i = tid; i < NG * HID; i += 256) p[i] = pooled[i];
    __syncthreads();
    for (int idx = tid; idx < NG * HID; idx += 256) {
        int g = idx >> 6, c = idx & 63;
        float acc = linb[c];
        for (int k = 0; k < HID; ++k) acc += p[g * HID + k] * linW[k * HID + c];
        z[idx] = fmaxf(acc, 0.f);
    }
    __syncthreads();
    for (int idx = tid; idx < NG * OUTC; idx += 256) {
        int g = idx >> 5, c = idx & 31;
        float acc = clfb[c];
        for (int k = 0; k < HID; ++k) acc += z[g * HID + k] * clfW[k * OUTC + c];
        out[idx] = acc;
    }
}

// ---------------- host side ----------------
extern "C" void kernel_launch(void* const* d_in, const int* in_sizes, int n_in,
                              void* d_out, int out_size, void* d_ws, size_t ws_size,
                              hipStream_t stream)
{
    const float* x      = (const float*)d_in[0];
    const int*   eidx   = (const int*)d_in[1];
    const int*   etype  = (const int*)d_in[2];
    const int*   batch  = (const int*)d_in[3];
    const float* enc_W  = (const float*)d_in[4];
    const float* enc_b  = (const float*)d_in[5];
    const float* w0     = (const float*)d_in[6];
    const float* q0     = (const float*)d_in[7];
    const float* k0     = (const float*)d_in[8];
    const float* b0     = (const float*)d_in[9];
    const float* w1     = (const float*)d_in[10];
    const float* q1     = (const float*)d_in[11];
    const float* k1     = (const float*)d_in[12];
    const float* b1     = (const float*)d_in[13];
    const float* lin_W  = (const float*)d_in[14];
    const float* lin_b  = (const float*)d_in[15];
    const float* clf_W  = (const float*)d_in[16];
    const float* clf_b  = (const float*)d_in[17];

    const int* srcp = eidx;
    const int* dstp = eidx + NE;

    char* wsb = (char*)d_ws;
    ushort16* h_bf    = (ushort16*)wsb;                 wsb += (size_t)NN * HID * 2;
    ushort16* hall_bf = (ushort16*)wsb;                 wsb += (size_t)NREL * NN * HID * 2;
    float*    sbuf    = (float*)wsb;                    wsb += (size_t)16 * NN * 4;
    float*    wqk0    = (float*)wsb;                    wsb += 16 * HID * 4;
    float*    wqk1    = (float*)wsb;                    wsb += 16 * HID * 4;
    float*    pooled  = (float*)wsb;                    wsb += NG * HID * 4;
    int*      rowptr  = (int*)wsb;                      wsb += (size_t)(NN + 64) * 4;
    int*      bucketHist = (int*)wsb;                   wsb += 256 * 4;
    int*      bucket_cur = (int*)wsb;                   wsb += 256 * 4;
    uint32*   ebin    = (uint32*)wsb;                   wsb += (size_t)NE * 4;
    uint32*   edges_s = (uint32*)wsb;                   wsb += (size_t)(NE + 64) * 4;

    // ---- prep: wqk both layers + zero {hist, cur, pooled} ----
    prep_kernel<<<33, 256, 0, stream>>>(w0, q0, k0, w1, q1, k1, wqk0, wqk1,
                                        bucketHist, bucket_cur, pooled);

    // ---- encoder + bucket histogram (fused) ----
    enchisto_kernel<<<ENC_BLOCKS + HISTO_BLOCKS, 256, 0, stream>>>(
        x, enc_W, enc_b, h_bf, dstp, bucketHist);

    // ---- CSR build (scan folded into binpass/sortpass) ----
    binpass<<<(NE + 4095) / 4096, 256, 0, stream>>>(srcp, dstp, etype,
                                                    bucketHist, bucket_cur, ebin);
    sortpass<<<NB2, 256, 0, stream>>>(ebin, bucketHist, rowptr, edges_s);

    const int SH_GRID = S_BLOCKS + 512 * NREL;   // 7221

    // ---- layer 0 ----
    sh_kernel<<<SH_GRID, 256, 0, stream>>>(h_bf, wqk0, w0, sbuf, hall_bf);
    agg_kernel<<<(NN + 3) / 4, 256, 0, stream>>>(rowptr, edges_s, sbuf, hall_bf, b0,
                                                 h_bf, (const int*)nullptr,
                                                 (float*)nullptr, 1);

    // ---- layer 1 (agg fused with global_add_pool) ----
    sh_kernel<<<SH_GRID, 256, 0, stream>>>(h_bf, wqk1, w1, sbuf, hall_bf);
    agg_kernel<<<(NN + 3) / 4, 256, 0, stream>>>(rowptr, edges_s, sbuf, hall_bf, b1,
                                                 (ushort16*)nullptr, batch, pooled, 0);

    // ---- head ----
    head_kernel<<<1, 256, 0, stream>>>(pooled, lin_W, lin_b, clf_W, clf_b, (float*)d_out);
}

// Round 14
// 171.616 us; speedup vs baseline: 4.5121x; 4.5121x over previous
//
#include <hip/hip_runtime.h>
#include <hip/hip_bf16.h>

#define NN 50000
#define NE 800000
#define INC 128
#define HID 64
#define OUTC 32
#define NREL 8
#define NG 64
#define SLOPE 0.2f
#define NB2 196          // dst buckets of 256 nodes
#define SCAP 6144        // sortpass LDS stage capacity (mean 4096, sd 64)
#define S_BLOCKS (NN / 16)   // 3125
#define HALL_BLOCKS (512 * NREL)
#define ENC_BLOCKS 512
#define HISTO_BLOCKS ((NE + 2047) / 2048)   // 391

typedef unsigned int uint32;
typedef unsigned short ushort16;
typedef __attribute__((ext_vector_type(8))) short short8;
typedef __attribute__((ext_vector_type(4))) short short4v;
typedef __attribute__((ext_vector_type(4))) float float4v;
typedef __attribute__((ext_vector_type(4))) int int4v;

__device__ __forceinline__ float bf2f(ushort16 u) {
    union { uint32 i; float f; } v; v.i = ((uint32)u) << 16; return v.f;
}
__device__ __forceinline__ ushort16 f2bf(float f) {
    union { float f; uint32 i; } v; v.f = f;
    uint32 i = v.i;
    return (ushort16)((i + 0x7FFFu + ((i >> 16) & 1u)) >> 16);   // RNE
}

// =====================================================================
// prep: wqk for both layers + zero {bucketHist, bucket_cur, pooled}
// =====================================================================
__global__ __launch_bounds__(256) void prep_kernel(
    const float* __restrict__ w0, const float* __restrict__ q0, const float* __restrict__ k0,
    const float* __restrict__ w1, const float* __restrict__ q1, const float* __restrict__ k1,
    float* __restrict__ wqk0, float* __restrict__ wqk1,
    int* __restrict__ bucketHist, int* __restrict__ bucket_cur,
    float* __restrict__ pooled)
{
    int b = blockIdx.x, t = threadIdx.x;
    if (b < 32) {
        const float* w  = (b < 16) ? w0 : w1;
        const float* qv = (b < 16) ? q0 : q1;
        const float* kv = (b < 16) ? k0 : k1;
        float* out = (b < 16) ? wqk0 : wqk1;
        int j = b & 15;
        int r = j & 7;
        const float* vv = (j < 8) ? qv : kv;
        if (t < 64) {
            const float* wr = w + ((size_t)r * HID + t) * HID;
            float acc = 0.f;
            for (int o = 0; o < HID; ++o) acc += wr[o] * vv[o];
            out[j * HID + t] = acc;
        }
    } else {
        if (t < NB2) { bucketHist[t] = 0; bucket_cur[t] = 0; }
        #pragma unroll
        for (int i = 0; i < (NG * HID) / 256; ++i) pooled[i * 256 + t] = 0.f;
    }
}

// =====================================================================
// enchisto: blocks [0,512) = encoder MFMA GEMM; blocks [512,903) = histo.
// =====================================================================
__global__ __launch_bounds__(256) void enchisto_kernel(const float* __restrict__ x,
    const float* __restrict__ W, const float* __restrict__ bias,
    ushort16* __restrict__ hb,
    const int* __restrict__ dst, int* __restrict__ bucketHist)
{
    __shared__ float lds[4][16 * 65];
    __shared__ int lh[NB2];
    int tid = threadIdx.x;

    if (blockIdx.x >= ENC_BLOCKS) {
        // ---------------- histo body ----------------
        for (int i = tid; i < NB2; i += 256) lh[i] = 0;
        __syncthreads();
        int base = (blockIdx.x - ENC_BLOCKS) * 2048;
        for (int i = tid; i < 2048; i += 256) {
            int idx = base + i;
            if (idx < NE) atomicAdd(&lh[dst[idx] >> 8], 1);
        }
        __syncthreads();
        for (int i = tid; i < NB2; i += 256) if (lh[i]) atomicAdd(&bucketHist[i], lh[i]);
        return;
    }

    // ---------------- enc body ----------------
    int wv = tid >> 6, lane = tid & 63;
    int g = lane >> 4, lr = lane & 15;

    short8 bf[4][4];                       // [colTile][kChunk]
    for (int t = 0; t < 4; ++t)
        for (int kc = 0; kc < 4; ++kc) {
            short8 v;
            #pragma unroll
            for (int j = 0; j < 8; ++j) {
                int k = kc * 32 + g * 8 + j;
                v[j] = (short)f2bf(W[k * HID + t * 16 + lr]);
            }
            bf[t][kc] = v;
        }

    float* myl = lds[wv];

    for (int tile = blockIdx.x * 4 + wv; tile < NN / 16; tile += ENC_BLOCKS * 4) {
        int row0 = tile * 16;
        const float4v* xp = (const float4v*)(x + (size_t)(row0 + lr) * INC);
        short8 af[4];
        #pragma unroll
        for (int kc = 0; kc < 4; ++kc) {
            float4v u0 = xp[kc * 8 + g * 2];
            float4v u1 = xp[kc * 8 + g * 2 + 1];
            short8 v;
            v[0] = (short)f2bf(u0[0]); v[1] = (short)f2bf(u0[1]);
            v[2] = (short)f2bf(u0[2]); v[3] = (short)f2bf(u0[3]);
            v[4] = (short)f2bf(u1[0]); v[5] = (short)f2bf(u1[1]);
            v[6] = (short)f2bf(u1[2]); v[7] = (short)f2bf(u1[3]);
            af[kc] = v;
        }
        float4v acc[4];
        #pragma unroll
        for (int t = 0; t < 4; ++t) { float4v z = {0.f,0.f,0.f,0.f}; acc[t] = z; }
        #pragma unroll
        for (int t = 0; t < 4; ++t)
            #pragma unroll
            for (int kc = 0; kc < 4; ++kc)
                acc[t] = __builtin_amdgcn_mfma_f32_16x16x32_bf16(af[kc], bf[t][kc], acc[t], 0, 0, 0);

        #pragma unroll
        for (int t = 0; t < 4; ++t)
            #pragma unroll
            for (int i = 0; i < 4; ++i)
                myl[(4 * g + i) * 65 + t * 16 + lr] = acc[t][i];
        __asm volatile("s_waitcnt lgkmcnt(0)" ::: "memory");

        int row = lane >> 2, cg = lane & 3;
        const float* srcp = myl + row * 65 + cg * 16;
        uint32 p[8];
        #pragma unroll
        for (int j = 0; j < 8; ++j) {
            float v0 = srcp[2 * j]     + bias[cg * 16 + 2 * j];
            float v1 = srcp[2 * j + 1] + bias[cg * 16 + 2 * j + 1];
            p[j] = (uint32)f2bf(v0) | ((uint32)f2bf(v1) << 16);
        }
        int4v s0 = {(int)p[0], (int)p[1], (int)p[2], (int)p[3]};
        int4v s1 = {(int)p[4], (int)p[5], (int)p[6], (int)p[7]};
        int4v* op = (int4v*)(hb + (size_t)(row0 + row) * HID + cg * 16);
        op[0] = s0; op[1] = s1;
        __asm volatile("s_waitcnt lgkmcnt(0)" ::: "memory");
    }
}

// =====================================================================
// binpass: bin edges into buckets. Computes the 196-bucket exclusive
// scan locally from bucketHist.
// =====================================================================
__global__ __launch_bounds__(256) void binpass(const int* __restrict__ src,
    const int* __restrict__ dst, const int* __restrict__ et,
    const int* __restrict__ bucketHist,
    int* __restrict__ bucket_cur, uint32* __restrict__ ebin)
{
    __shared__ int ps[256], baseSh[NB2];
    __shared__ int lh[NB2], lbase[NB2], lcur[NB2];
    int t = threadIdx.x;

    int v = (t < NB2) ? bucketHist[t] : 0;
    ps[t] = v;
    __syncthreads();
    for (int off = 1; off < 256; off <<= 1) {
        int tv = (t >= off) ? ps[t - off] : 0;
        __syncthreads();
        ps[t] += tv;
        __syncthreads();
    }
    if (t < NB2) baseSh[t] = ps[t] - v;

    for (int i = t; i < NB2; i += 256) { lh[i] = 0; lcur[i] = 0; }
    __syncthreads();

    int base = blockIdx.x * 4096;
    uint32 rec[16]; int bkt[16];
    #pragma unroll
    for (int i = 0; i < 16; ++i) {
        int idx = base + i * 256 + t;
        bkt[i] = -1;
        if (idx < NE) {
            int s = src[idx], d = dst[idx], r = et[idx];
            rec[i] = (uint32)s | ((uint32)r << 16) | ((uint32)(d & 255) << 19);
            bkt[i] = d >> 8;
            atomicAdd(&lh[bkt[i]], 1);
        }
    }
    __syncthreads();
    for (int i = t; i < NB2; i += 256)
        if (lh[i]) lbase[i] = baseSh[i] + atomicAdd(&bucket_cur[i], lh[i]);
    __syncthreads();
    #pragma unroll
    for (int i = 0; i < 16; ++i) {
        if (bkt[i] >= 0) {
            int lpos = atomicAdd(&lcur[bkt[i]], 1);
            ebin[lbase[bkt[i]] + lpos] = rec[i];
        }
    }
}

// =====================================================================
// shsort: fused {sortpass (layer0 only)} + s (scores) + hall (transform).
// WITH_SORT: blocks [0,NB2) run the per-bucket fine sort (writes rowptr,
// edges_s); remaining blocks: [0,S_BLOCKS) s-body, then hall-body.
// One 28KB shared arena, carved per branch (keeps occupancy).
// =====================================================================
template<bool WITH_SORT>
__global__ __launch_bounds__(256) void shsort_kernel(const ushort16* __restrict__ hb,
    const float* __restrict__ wqk, const float* __restrict__ w,
    float* __restrict__ sbuf, ushort16* __restrict__ hall,
    const uint32* __restrict__ ebin, const int* __restrict__ bucketHist,
    int* __restrict__ rowptr, uint32* __restrict__ edges_s)
{
    __shared__ __attribute__((aligned(16))) char smem[28672];
    int tid = threadIdx.x;
    int b = blockIdx.x;

    if (WITH_SORT) {
        if (b < NB2) {
            // ---------------- sortpass body ----------------
            uint32* stage = (uint32*)smem;                    // 24576 B
            int* cnt256 = (int*)(smem + 24576);               // 1 KB
            int* ps     = (int*)(smem + 24576 + 1024);        // 1 KB
            int* cur    = (int*)(smem + 24576 + 2048);        // 1 KB
            __shared__ int segSh[2];
            int t = tid;

            int v = (t < NB2) ? bucketHist[t] : 0;
            ps[t] = v;
            __syncthreads();
            for (int off = 1; off < 256; off <<= 1) {
                int tv = (t >= off) ? ps[t - off] : 0;
                __syncthreads();
                ps[t] += tv;
                __syncthreads();
            }
            if (t == b) { segSh[0] = ps[t] - v; segSh[1] = ps[t]; }
            __syncthreads();
            int seg0 = segSh[0], seg1 = segSh[1];
            int cnt = seg1 - seg0;

            cnt256[t] = 0;
            __syncthreads();
            for (int i = t; i < cnt; i += 256) {
                uint32 rec = ebin[seg0 + i];
                atomicAdd(&cnt256[(rec >> 19) & 255], 1);
            }
            __syncthreads();
            int v2 = cnt256[t];
            ps[t] = v2;
            __syncthreads();
            for (int off = 1; off < 256; off <<= 1) {
                int tv = (t >= off) ? ps[t - off] : 0;
                __syncthreads();
                ps[t] += tv;
                __syncthreads();
            }
            int excl = ps[t] - v2;
            int node = (b << 8) + t;
            if (node < NN) rowptr[node] = seg0 + excl;
            if (b == NB2 - 1 && t == 0) rowptr[NN] = NE;
            cur[t] = excl;
            __syncthreads();
            for (int i = t; i < cnt; i += 256) {
                uint32 rec = ebin[seg0 + i];
                int lpos = atomicAdd(&cur[(rec >> 19) & 255], 1);
                if (lpos < SCAP) stage[lpos] = rec;
                else edges_s[seg0 + lpos] = rec;
            }
            __syncthreads();
            int lim = cnt < SCAP ? cnt : SCAP;
            for (int i = t; i < lim; i += 256) edges_s[seg0 + i] = stage[i];
            return;
        }
        b -= NB2;
    }

    if (b < S_BLOCKS) {
        // ---------------- s body ----------------
        float* Ws = (float*)smem;                             // 16*65*4 = 4160 B
        short4v* Hs = (short4v*)(smem + 4160);                // 16*17*8 = 2176 B
        for (int i = tid; i < 16 * HID; i += 256) Ws[(i >> 6) * 65 + (i & 63)] = wqk[i];
        int n0 = b * 16;
        {
            int row = tid >> 4, ch = tid & 15;
            Hs[row * 17 + ch] = *(const short4v*)(hb + (size_t)(n0 + row) * HID + ch * 4);
        }
        __syncthreads();
        int j = tid & 15, nl = tid >> 4;
        short4v hreg[16];
        #pragma unroll
        for (int c = 0; c < 16; ++c) hreg[c] = Hs[nl * 17 + c];
        float acc = 0.f;
        #pragma unroll
        for (int c = 0; c < 16; ++c)
            #pragma unroll
            for (int u = 0; u < 4; ++u)
                acc += bf2f((ushort16)hreg[c][u]) * Ws[j * 65 + c * 4 + u];
        sbuf[(size_t)j * NN + n0 + nl] = acc;
        return;
    }

    // ---------------- hall body ----------------
    int hb_ = b - S_BLOCKS;
    int r = hb_ >> 9, xb = hb_ & 511;
    int wv = tid >> 6, lane = tid & 63;
    int g = lane >> 4, lr = lane & 15;
    const float* wr = w + (size_t)r * HID * HID;

    short8 bfr[4][2];
    for (int t = 0; t < 4; ++t)
        for (int kc = 0; kc < 2; ++kc) {
            short8 v;
            #pragma unroll
            for (int j = 0; j < 8; ++j) {
                int k = kc * 32 + g * 8 + j;
                v[j] = (short)f2bf(wr[k * HID + t * 16 + lr]);
            }
            bfr[t][kc] = v;
        }

    float* myl = (float*)smem + wv * (16 * 65);
    ushort16* outr = hall + (size_t)r * NN * HID;

    for (int tile = xb * 4 + wv; tile < NN / 16; tile += 512 * 4) {
        int row0 = tile * 16;
        const short8* ap = (const short8*)(hb + (size_t)(row0 + lr) * HID);
        short8 a0 = ap[g];
        short8 a1 = ap[4 + g];
        float4v acc[4];
        #pragma unroll
        for (int t = 0; t < 4; ++t) { float4v z = {0.f,0.f,0.f,0.f}; acc[t] = z; }
        #pragma unroll
        for (int t = 0; t < 4; ++t) {
            acc[t] = __builtin_amdgcn_mfma_f32_16x16x32_bf16(a0, bfr[t][0], acc[t], 0, 0, 0);
            acc[t] = __builtin_amdgcn_mfma_f32_16x16x32_bf16(a1, bfr[t][1], acc[t], 0, 0, 0);
        }
        #pragma unroll
        for (int t = 0; t < 4; ++t)
            #pragma unroll
            for (int i = 0; i < 4; ++i)
                myl[(4 * g + i) * 65 + t * 16 + lr] = acc[t][i];
        __asm volatile("s_waitcnt lgkmcnt(0)" ::: "memory");

        int row = lane >> 2, cg = lane & 3;
        const float* srcp = myl + row * 65 + cg * 16;
        uint32 p[8];
        #pragma unroll
        for (int j = 0; j < 8; ++j)
            p[j] = (uint32)f2bf(srcp[2 * j]) | ((uint32)f2bf(srcp[2 * j + 1]) << 16);
        int4v s0 = {(int)p[0], (int)p[1], (int)p[2], (int)p[3]};
        int4v s1 = {(int)p[4], (int)p[5], (int)p[6], (int)p[7]};
        int4v* op = (int4v*)(outr + (size_t)(row0 + row) * HID + cg * 16);
        op[0] = s0; op[1] = s1;
        __asm volatile("s_waitcnt lgkmcnt(0)" ::: "memory");
    }
}

// =====================================================================
// Fused per-dst softmax + aggregate + bias (+relu).
// One wave per node; 8 groups of 8 lanes; 2 edges in flight per group.
// =====================================================================
__global__ __launch_bounds__(256) void agg_kernel(const int* __restrict__ rowptr,
    const uint32* __restrict__ edges, const float* __restrict__ sbuf,
    const ushort16* __restrict__ hall, const float* __restrict__ bias,
    ushort16* __restrict__ out_bf, float* __restrict__ out_f32, int do_relu)
{
    int wv = threadIdx.x >> 6, lane = threadIdx.x & 63;
    int d = blockIdx.x * 4 + wv;
    if (d >= NN) return;
    int row0 = rowptr[d];
    int deg = rowptr[d + 1] - row0;
    int g = lane >> 3, cl = lane & 7;

    float myq = (lane < 8) ? sbuf[lane * NN + d] : 0.f;

    float acc[8];
    #pragma unroll
    for (int u = 0; u < 8; ++u) acc[u] = 0.f;
    float ssum = 0.f;

    for (int base = 0; base < deg; base += 16) {
        int j0 = base + g, j1 = j0 + 8;
        bool v0 = j0 < deg, v1 = j1 < deg;
        uint32 pk0 = v0 ? edges[row0 + j0] : 0u;
        uint32 pk1 = v1 ? edges[row0 + j1] : 0u;
        int s0 = (int)(pk0 & 0xFFFFu), r0 = (int)((pk0 >> 16) & 7u);
        int s1 = (int)(pk1 & 0xFFFFu), r1 = (int)((pk1 >> 16) & 7u);
        float sc0 = sbuf[(8 + r0) * NN + s0];
        float sc1 = sbuf[(8 + r1) * NN + s1];
        short8 hv0 = *(const short8*)(hall + ((size_t)r0 * NN + s0) * HID + cl * 8);
        short8 hv1 = *(const short8*)(hall + ((size_t)r1 * NN + s1) * HID + cl * 8);
        float a0 = __shfl(myq, r0) + sc0; a0 = (a0 > 0.f) ? a0 : SLOPE * a0;
        float a1 = __shfl(myq, r1) + sc1; a1 = (a1 > 0.f) ? a1 : SLOPE * a1;
        float ex0 = v0 ? __expf(a0) : 0.f;
        float ex1 = v1 ? __expf(a1) : 0.f;
        ssum += ex0 + ex1;
        #pragma unroll
        for (int u = 0; u < 8; ++u)
            acc[u] += ex0 * bf2f((ushort16)hv0[u]) + ex1 * bf2f((ushort16)hv1[u]);
    }

    #pragma unroll
    for (int o = 8; o < 64; o <<= 1) {
        ssum += __shfl_xor(ssum, o);
        #pragma unroll
        for (int u = 0; u < 8; ++u) acc[u] += __shfl_xor(acc[u], o);
    }

    if (lane < 8) {
        float inv = 1.f / fmaxf(ssum, 1e-16f);
        float o_[8];
        #pragma unroll
        for (int u = 0; u < 8; ++u) o_[u] = acc[u] * inv + bias[lane * 8 + u];
        if (do_relu) {
            uint32 p[4];
            #pragma unroll
            for (int u = 0; u < 4; ++u) {
                float v0 = fmaxf(o_[2 * u], 0.f);
                float v1 = fmaxf(o_[2 * u + 1], 0.f);
                p[u] = (uint32)f2bf(v0) | ((uint32)f2bf(v1) << 16);
            }
            int4v pk4 = {(int)p[0], (int)p[1], (int)p[2], (int)p[3]};
            *(int4v*)(out_bf + (size_t)d * HID + lane * 8) = pk4;
        } else {
            float4v v0 = {o_[0], o_[1], o_[2], o_[3]};
            float4v v1 = {o_[4], o_[5], o_[6], o_[7]};
            float4v* op = (float4v*)(out_f32 + (size_t)d * HID + lane * 8);
            op[0] = v0; op[1] = v1;
        }
    }
}

// ---------------- pooling (batch sorted -> run-length accumulate) ----------------
__global__ void pool_kernel(const float* __restrict__ h, const int* __restrict__ batch,
                            float* __restrict__ pooled)
{
    int t = blockIdx.x * 256 + threadIdx.x;
    int c = t & 63;
    int chunk = t >> 6;
    if (chunk >= NN / 16) return;
    int n0 = chunk * 16;
    float acc = 0.f;
    int cur = batch[n0];
    for (int n = n0; n < n0 + 16; ++n) {
        int b = batch[n];
        if (b != cur) { atomicAdd(&pooled[cur * HID + c], acc); acc = 0.f; cur = b; }
        acc += h[(size_t)n * HID + c];
    }
    atomicAdd(&pooled[cur * HID + c], acc);
}

// ---------------- head ----------------
__global__ __launch_bounds__(256) void head_kernel(const float* __restrict__ pooled,
    const float* __restrict__ linW, const float* __restrict__ linb,
    const float* __restrict__ clfW, const float* __restrict__ clfb,
    float* __restrict__ out)
{
    __shared__ float z[NG * HID];
    __shared__ float p[NG * HID];
    int tid = threadIdx.x;
    for (int i = tid; i < NG * HID; i += 256) p[i] = pooled[i];
    __syncthreads();
    for (int idx = tid; idx < NG * HID; idx += 256) {
        int g = idx >> 6, c = idx & 63;
        float acc = linb[c];
        for (int k = 0; k < HID; ++k) acc += p[g * HID + k] * linW[k * HID + c];
        z[idx] = fmaxf(acc, 0.f);
    }
    __syncthreads();
    for (int idx = tid; idx < NG * OUTC; idx += 256) {
        int g = idx >> 5, c = idx & 31;
        float acc = clfb[c];
        for (int k = 0; k < HID; ++k) acc += z[g * HID + k] * clfW[k * OUTC + c];
        out[idx] = acc;
    }
}

// ---------------- host side ----------------
extern "C" void kernel_launch(void* const* d_in, const int* in_sizes, int n_in,
                              void* d_out, int out_size, void* d_ws, size_t ws_size,
                              hipStream_t stream)
{
    const float* x      = (const float*)d_in[0];
    const int*   eidx   = (const int*)d_in[1];
    const int*   etype  = (const int*)d_in[2];
    const int*   batch  = (const int*)d_in[3];
    const float* enc_W  = (const float*)d_in[4];
    const float* enc_b  = (const float*)d_in[5];
    const float* w0     = (const float*)d_in[6];
    const float* q0     = (const float*)d_in[7];
    const float* k0     = (const float*)d_in[8];
    const float* b0     = (const float*)d_in[9];
    const float* w1     = (const float*)d_in[10];
    const float* q1     = (const float*)d_in[11];
    const float* k1     = (const float*)d_in[12];
    const float* b1     = (const float*)d_in[13];
    const float* lin_W  = (const float*)d_in[14];
    const float* lin_b  = (const float*)d_in[15];
    const float* clf_W  = (const float*)d_in[16];
    const float* clf_b  = (const float*)d_in[17];

    const int* srcp = eidx;
    const int* dstp = eidx + NE;

    char* wsb = (char*)d_ws;
    ushort16* h_bf    = (ushort16*)wsb;                 wsb += (size_t)NN * HID * 2;
    ushort16* hall_bf = (ushort16*)wsb;                 wsb += (size_t)NREL * NN * HID * 2;
    float*    h_f     = (float*)wsb;                    wsb += (size_t)NN * HID * 4;
    float*    sbuf    = (float*)wsb;                    wsb += (size_t)16 * NN * 4;
    float*    wqk0    = (float*)wsb;                    wsb += 16 * HID * 4;
    float*    wqk1    = (float*)wsb;                    wsb += 16 * HID * 4;
    float*    pooled  = (float*)wsb;                    wsb += NG * HID * 4;
    int*      rowptr  = (int*)wsb;                      wsb += (size_t)(NN + 64) * 4;
    int*      bucketHist = (int*)wsb;                   wsb += 256 * 4;
    int*      bucket_cur = (int*)wsb;                   wsb += 256 * 4;
    uint32*   ebin    = (uint32*)wsb;                   wsb += (size_t)NE * 4;
    uint32*   edges_s = (uint32*)wsb;                   wsb += (size_t)(NE + 64) * 4;

    // ---- prep: wqk both layers + zero {hist, cur, pooled} ----
    prep_kernel<<<33, 256, 0, stream>>>(w0, q0, k0, w1, q1, k1, wqk0, wqk1,
                                        bucketHist, bucket_cur, pooled);

    // ---- encoder + bucket histogram (fused) ----
    enchisto_kernel<<<ENC_BLOCKS + HISTO_BLOCKS, 256, 0, stream>>>(
        x, enc_W, enc_b, h_bf, dstp, bucketHist);

    // ---- bin edges into buckets ----
    binpass<<<(NE + 4095) / 4096, 256, 0, stream>>>(srcp, dstp, etype,
                                                    bucketHist, bucket_cur, ebin);

    // ---- layer 0 (sortpass fused into sh dispatch) ----
    shsort_kernel<true><<<NB2 + S_BLOCKS + HALL_BLOCKS, 256, 0, stream>>>(
        h_bf, wqk0, w0, sbuf, hall_bf, ebin, bucketHist, rowptr, edges_s);
    agg_kernel<<<(NN + 3) / 4, 256, 0, stream>>>(rowptr, edges_s, sbuf, hall_bf, b0,
                                                 h_bf, (float*)nullptr, 1);

    // ---- layer 1 ----
    shsort_kernel<false><<<S_BLOCKS + HALL_BLOCKS, 256, 0, stream>>>(
        h_bf, wqk1, w1, sbuf, hall_bf, ebin, bucketHist, rowptr, edges_s);
    agg_kernel<<<(NN + 3) / 4, 256, 0, stream>>>(rowptr, edges_s, sbuf, hall_bf, b1,
                                                 (ushort16*)nullptr, h_f, 0);

    // ---- pool + head ----
    pool_kernel<<<(NN / 16 * HID + 255) / 256, 256, 0, stream>>>(h_f, batch, pooled);
    head_kernel<<<1, 256, 0, stream>>>(pooled, lin_W, lin_b, clf_W, clf_b, (float*)d_out);
}

// Round 15
// 171.592 us; speedup vs baseline: 4.5127x; 1.0001x over previous
//
#include <hip/hip_runtime.h>
#include <hip/hip_bf16.h>

#define NN 50000
#define NE 800000
#define INC 128
#define HID 64
#define OUTC 32
#define NREL 8
#define NG 64
#define SLOPE 0.2f
#define NB2 196          // dst buckets of 256 nodes
#define SCAP 6144        // sortpass LDS stage capacity (mean 4096, sd 64)
#define S_BLOCKS (NN / 16)   // 3125
#define HALL_BLOCKS (512 * NREL)
#define ENC_BLOCKS 512
#define HISTO_BLOCKS ((NE + 2047) / 2048)   // 391

typedef unsigned int uint32;
typedef unsigned short ushort16;
typedef __attribute__((ext_vector_type(8))) short short8;
typedef __attribute__((ext_vector_type(4))) short short4v;
typedef __attribute__((ext_vector_type(4))) float float4v;
typedef __attribute__((ext_vector_type(4))) int int4v;

__device__ __forceinline__ float bf2f(ushort16 u) {
    union { uint32 i; float f; } v; v.i = ((uint32)u) << 16; return v.f;
}
__device__ __forceinline__ ushort16 f2bf(float f) {
    union { float f; uint32 i; } v; v.f = f;
    uint32 i = v.i;
    return (ushort16)((i + 0x7FFFu + ((i >> 16) & 1u)) >> 16);   // RNE
}

// =====================================================================
// prep: wqk for both layers + zero {bucketHist, bucket_cur, pooled}
// =====================================================================
__global__ __launch_bounds__(256) void prep_kernel(
    const float* __restrict__ w0, const float* __restrict__ q0, const float* __restrict__ k0,
    const float* __restrict__ w1, const float* __restrict__ q1, const float* __restrict__ k1,
    float* __restrict__ wqk0, float* __restrict__ wqk1,
    int* __restrict__ bucketHist, int* __restrict__ bucket_cur,
    float* __restrict__ pooled)
{
    int b = blockIdx.x, t = threadIdx.x;
    if (b < 32) {
        const float* w  = (b < 16) ? w0 : w1;
        const float* qv = (b < 16) ? q0 : q1;
        const float* kv = (b < 16) ? k0 : k1;
        float* out = (b < 16) ? wqk0 : wqk1;
        int j = b & 15;
        int r = j & 7;
        const float* vv = (j < 8) ? qv : kv;
        if (t < 64) {
            const float* wr = w + ((size_t)r * HID + t) * HID;
            float acc = 0.f;
            for (int o = 0; o < HID; ++o) acc += wr[o] * vv[o];
            out[j * HID + t] = acc;
        }
    } else {
        if (t < NB2) { bucketHist[t] = 0; bucket_cur[t] = 0; }
        #pragma unroll
        for (int i = 0; i < (NG * HID) / 256; ++i) pooled[i * 256 + t] = 0.f;
    }
}

// =====================================================================
// enchisto: blocks [0,512) = encoder MFMA GEMM; blocks [512,903) = histo.
// =====================================================================
__global__ __launch_bounds__(256) void enchisto_kernel(const float* __restrict__ x,
    const float* __restrict__ W, const float* __restrict__ bias,
    ushort16* __restrict__ hb,
    const int* __restrict__ dst, int* __restrict__ bucketHist)
{
    __shared__ float lds[4][16 * 65];
    __shared__ int lh[NB2];
    int tid = threadIdx.x;

    if (blockIdx.x >= ENC_BLOCKS) {
        // ---------------- histo body ----------------
        for (int i = tid; i < NB2; i += 256) lh[i] = 0;
        __syncthreads();
        int base = (blockIdx.x - ENC_BLOCKS) * 2048;
        for (int i = tid; i < 2048; i += 256) {
            int idx = base + i;
            if (idx < NE) atomicAdd(&lh[dst[idx] >> 8], 1);
        }
        __syncthreads();
        for (int i = tid; i < NB2; i += 256) if (lh[i]) atomicAdd(&bucketHist[i], lh[i]);
        return;
    }

    // ---------------- enc body ----------------
    int wv = tid >> 6, lane = tid & 63;
    int g = lane >> 4, lr = lane & 15;

    short8 bf[4][4];                       // [colTile][kChunk]
    for (int t = 0; t < 4; ++t)
        for (int kc = 0; kc < 4; ++kc) {
            short8 v;
            #pragma unroll
            for (int j = 0; j < 8; ++j) {
                int k = kc * 32 + g * 8 + j;
                v[j] = (short)f2bf(W[k * HID + t * 16 + lr]);
            }
            bf[t][kc] = v;
        }

    float* myl = lds[wv];

    for (int tile = blockIdx.x * 4 + wv; tile < NN / 16; tile += ENC_BLOCKS * 4) {
        int row0 = tile * 16;
        const float4v* xp = (const float4v*)(x + (size_t)(row0 + lr) * INC);
        short8 af[4];
        #pragma unroll
        for (int kc = 0; kc < 4; ++kc) {
            float4v u0 = xp[kc * 8 + g * 2];
            float4v u1 = xp[kc * 8 + g * 2 + 1];
            short8 v;
            v[0] = (short)f2bf(u0[0]); v[1] = (short)f2bf(u0[1]);
            v[2] = (short)f2bf(u0[2]); v[3] = (short)f2bf(u0[3]);
            v[4] = (short)f2bf(u1[0]); v[5] = (short)f2bf(u1[1]);
            v[6] = (short)f2bf(u1[2]); v[7] = (short)f2bf(u1[3]);
            af[kc] = v;
        }
        float4v acc[4];
        #pragma unroll
        for (int t = 0; t < 4; ++t) { float4v z = {0.f,0.f,0.f,0.f}; acc[t] = z; }
        #pragma unroll
        for (int t = 0; t < 4; ++t)
            #pragma unroll
            for (int kc = 0; kc < 4; ++kc)
                acc[t] = __builtin_amdgcn_mfma_f32_16x16x32_bf16(af[kc], bf[t][kc], acc[t], 0, 0, 0);

        #pragma unroll
        for (int t = 0; t < 4; ++t)
            #pragma unroll
            for (int i = 0; i < 4; ++i)
                myl[(4 * g + i) * 65 + t * 16 + lr] = acc[t][i];
        __asm volatile("s_waitcnt lgkmcnt(0)" ::: "memory");

        int row = lane >> 2, cg = lane & 3;
        const float* srcp = myl + row * 65 + cg * 16;
        uint32 p[8];
        #pragma unroll
        for (int j = 0; j < 8; ++j) {
            float v0 = srcp[2 * j]     + bias[cg * 16 + 2 * j];
            float v1 = srcp[2 * j + 1] + bias[cg * 16 + 2 * j + 1];
            p[j] = (uint32)f2bf(v0) | ((uint32)f2bf(v1) << 16);
        }
        int4v s0 = {(int)p[0], (int)p[1], (int)p[2], (int)p[3]};
        int4v s1 = {(int)p[4], (int)p[5], (int)p[6], (int)p[7]};
        int4v* op = (int4v*)(hb + (size_t)(row0 + row) * HID + cg * 16);
        op[0] = s0; op[1] = s1;
        __asm volatile("s_waitcnt lgkmcnt(0)" ::: "memory");
    }
}

// =====================================================================
// binpass: bin edges into buckets. Computes the 196-bucket exclusive
// scan locally from bucketHist.
// =====================================================================
__global__ __launch_bounds__(256) void binpass(const int* __restrict__ src,
    const int* __restrict__ dst, const int* __restrict__ et,
    const int* __restrict__ bucketHist,
    int* __restrict__ bucket_cur, uint32* __restrict__ ebin)
{
    __shared__ int ps[256], baseSh[NB2];
    __shared__ int lh[NB2], lbase[NB2], lcur[NB2];
    int t = threadIdx.x;

    int v = (t < NB2) ? bucketHist[t] : 0;
    ps[t] = v;
    __syncthreads();
    for (int off = 1; off < 256; off <<= 1) {
        int tv = (t >= off) ? ps[t - off] : 0;
        __syncthreads();
        ps[t] += tv;
        __syncthreads();
    }
    if (t < NB2) baseSh[t] = ps[t] - v;

    for (int i = t; i < NB2; i += 256) { lh[i] = 0; lcur[i] = 0; }
    __syncthreads();

    int base = blockIdx.x * 4096;
    uint32 rec[16]; int bkt[16];
    #pragma unroll
    for (int i = 0; i < 16; ++i) {
        int idx = base + i * 256 + t;
        bkt[i] = -1;
        if (idx < NE) {
            int s = src[idx], d = dst[idx], r = et[idx];
            rec[i] = (uint32)s | ((uint32)r << 16) | ((uint32)(d & 255) << 19);
            bkt[i] = d >> 8;
            atomicAdd(&lh[bkt[i]], 1);
        }
    }
    __syncthreads();
    for (int i = t; i < NB2; i += 256)
        if (lh[i]) lbase[i] = baseSh[i] + atomicAdd(&bucket_cur[i], lh[i]);
    __syncthreads();
    #pragma unroll
    for (int i = 0; i < 16; ++i) {
        if (bkt[i] >= 0) {
            int lpos = atomicAdd(&lcur[bkt[i]], 1);
            ebin[lbase[bkt[i]] + lpos] = rec[i];
        }
    }
}

// =====================================================================
// shsort: fused {sortpass (layer0 only)} + s (scores) + hall (transform).
// =====================================================================
template<bool WITH_SORT>
__global__ __launch_bounds__(256) void shsort_kernel(const ushort16* __restrict__ hb,
    const float* __restrict__ wqk, const float* __restrict__ w,
    float* __restrict__ sbuf, ushort16* __restrict__ hall,
    const uint32* __restrict__ ebin, const int* __restrict__ bucketHist,
    int* __restrict__ rowptr, uint32* __restrict__ edges_s)
{
    __shared__ __attribute__((aligned(16))) char smem[28672];
    int tid = threadIdx.x;
    int b = blockIdx.x;

    if (WITH_SORT) {
        if (b < NB2) {
            // ---------------- sortpass body ----------------
            uint32* stage = (uint32*)smem;                    // 24576 B
            int* cnt256 = (int*)(smem + 24576);               // 1 KB
            int* ps     = (int*)(smem + 24576 + 1024);        // 1 KB
            int* cur    = (int*)(smem + 24576 + 2048);        // 1 KB
            __shared__ int segSh[2];
            int t = tid;

            int v = (t < NB2) ? bucketHist[t] : 0;
            ps[t] = v;
            __syncthreads();
            for (int off = 1; off < 256; off <<= 1) {
                int tv = (t >= off) ? ps[t - off] : 0;
                __syncthreads();
                ps[t] += tv;
                __syncthreads();
            }
            if (t == b) { segSh[0] = ps[t] - v; segSh[1] = ps[t]; }
            __syncthreads();
            int seg0 = segSh[0], seg1 = segSh[1];
            int cnt = seg1 - seg0;

            cnt256[t] = 0;
            __syncthreads();
            for (int i = t; i < cnt; i += 256) {
                uint32 rec = ebin[seg0 + i];
                atomicAdd(&cnt256[(rec >> 19) & 255], 1);
            }
            __syncthreads();
            int v2 = cnt256[t];
            ps[t] = v2;
            __syncthreads();
            for (int off = 1; off < 256; off <<= 1) {
                int tv = (t >= off) ? ps[t - off] : 0;
                __syncthreads();
                ps[t] += tv;
                __syncthreads();
            }
            int excl = ps[t] - v2;
            int node = (b << 8) + t;
            if (node < NN) rowptr[node] = seg0 + excl;
            if (b == NB2 - 1 && t == 0) rowptr[NN] = NE;
            cur[t] = excl;
            __syncthreads();
            for (int i = t; i < cnt; i += 256) {
                uint32 rec = ebin[seg0 + i];
                int lpos = atomicAdd(&cur[(rec >> 19) & 255], 1);
                if (lpos < SCAP) stage[lpos] = rec;
                else edges_s[seg0 + lpos] = rec;
            }
            __syncthreads();
            int lim = cnt < SCAP ? cnt : SCAP;
            for (int i = t; i < lim; i += 256) edges_s[seg0 + i] = stage[i];
            return;
        }
        b -= NB2;
    }

    if (b < S_BLOCKS) {
        // ---------------- s body ----------------
        float* Ws = (float*)smem;                             // 4160 B
        short4v* Hs = (short4v*)(smem + 4160);                // 2176 B
        for (int i = tid; i < 16 * HID; i += 256) Ws[(i >> 6) * 65 + (i & 63)] = wqk[i];
        int n0 = b * 16;
        {
            int row = tid >> 4, ch = tid & 15;
            Hs[row * 17 + ch] = *(const short4v*)(hb + (size_t)(n0 + row) * HID + ch * 4);
        }
        __syncthreads();
        int j = tid & 15, nl = tid >> 4;
        short4v hreg[16];
        #pragma unroll
        for (int c = 0; c < 16; ++c) hreg[c] = Hs[nl * 17 + c];
        float acc = 0.f;
        #pragma unroll
        for (int c = 0; c < 16; ++c)
            #pragma unroll
            for (int u = 0; u < 4; ++u)
                acc += bf2f((ushort16)hreg[c][u]) * Ws[j * 65 + c * 4 + u];
        sbuf[(size_t)j * NN + n0 + nl] = acc;
        return;
    }

    // ---------------- hall body ----------------
    int hb_ = b - S_BLOCKS;
    int r = hb_ >> 9, xb = hb_ & 511;
    int wv = tid >> 6, lane = tid & 63;
    int g = lane >> 4, lr = lane & 15;
    const float* wr = w + (size_t)r * HID * HID;

    short8 bfr[4][2];
    for (int t = 0; t < 4; ++t)
        for (int kc = 0; kc < 2; ++kc) {
            short8 v;
            #pragma unroll
            for (int j = 0; j < 8; ++j) {
                int k = kc * 32 + g * 8 + j;
                v[j] = (short)f2bf(wr[k * HID + t * 16 + lr]);
            }
            bfr[t][kc] = v;
        }

    float* myl = (float*)smem + wv * (16 * 65);
    ushort16* outr = hall + (size_t)r * NN * HID;

    for (int tile = xb * 4 + wv; tile < NN / 16; tile += 512 * 4) {
        int row0 = tile * 16;
        const short8* ap = (const short8*)(hb + (size_t)(row0 + lr) * HID);
        short8 a0 = ap[g];
        short8 a1 = ap[4 + g];
        float4v acc[4];
        #pragma unroll
        for (int t = 0; t < 4; ++t) { float4v z = {0.f,0.f,0.f,0.f}; acc[t] = z; }
        #pragma unroll
        for (int t = 0; t < 4; ++t) {
            acc[t] = __builtin_amdgcn_mfma_f32_16x16x32_bf16(a0, bfr[t][0], acc[t], 0, 0, 0);
            acc[t] = __builtin_amdgcn_mfma_f32_16x16x32_bf16(a1, bfr[t][1], acc[t], 0, 0, 0);
        }
        #pragma unroll
        for (int t = 0; t < 4; ++t)
            #pragma unroll
            for (int i = 0; i < 4; ++i)
                myl[(4 * g + i) * 65 + t * 16 + lr] = acc[t][i];
        __asm volatile("s_waitcnt lgkmcnt(0)" ::: "memory");

        int row = lane >> 2, cg = lane & 3;
        const float* srcp = myl + row * 65 + cg * 16;
        uint32 p[8];
        #pragma unroll
        for (int j = 0; j < 8; ++j)
            p[j] = (uint32)f2bf(srcp[2 * j]) | ((uint32)f2bf(srcp[2 * j + 1]) << 16);
        int4v s0 = {(int)p[0], (int)p[1], (int)p[2], (int)p[3]};
        int4v s1 = {(int)p[4], (int)p[5], (int)p[6], (int)p[7]};
        int4v* op = (int4v*)(outr + (size_t)(row0 + row) * HID + cg * 16);
        op[0] = s0; op[1] = s1;
        __asm volatile("s_waitcnt lgkmcnt(0)" ::: "memory");
    }
}

// =====================================================================
// Fused per-dst softmax + aggregate + bias (+relu).
// One wave per node; 8 groups of 8 lanes; 2 edges in flight per group.
// Output always bf16 (layer 1 feeds the bf16 pool path).
// =====================================================================
__global__ __launch_bounds__(256) void agg_kernel(const int* __restrict__ rowptr,
    const uint32* __restrict__ edges, const float* __restrict__ sbuf,
    const ushort16* __restrict__ hall, const float* __restrict__ bias,
    ushort16* __restrict__ out_bf, int do_relu)
{
    int wv = threadIdx.x >> 6, lane = threadIdx.x & 63;
    int d = blockIdx.x * 4 + wv;
    if (d >= NN) return;
    int row0 = rowptr[d];
    int deg = rowptr[d + 1] - row0;
    int g = lane >> 3, cl = lane & 7;

    float myq = (lane < 8) ? sbuf[lane * NN + d] : 0.f;

    float acc[8];
    #pragma unroll
    for (int u = 0; u < 8; ++u) acc[u] = 0.f;
    float ssum = 0.f;

    for (int base = 0; base < deg; base += 16) {
        int j0 = base + g, j1 = j0 + 8;
        bool v0 = j0 < deg, v1 = j1 < deg;
        uint32 pk0 = v0 ? edges[row0 + j0] : 0u;
        uint32 pk1 = v1 ? edges[row0 + j1] : 0u;
        int s0 = (int)(pk0 & 0xFFFFu), r0 = (int)((pk0 >> 16) & 7u);
        int s1 = (int)(pk1 & 0xFFFFu), r1 = (int)((pk1 >> 16) & 7u);
        float sc0 = sbuf[(8 + r0) * NN + s0];
        float sc1 = sbuf[(8 + r1) * NN + s1];
        short8 hv0 = *(const short8*)(hall + ((size_t)r0 * NN + s0) * HID + cl * 8);
        short8 hv1 = *(const short8*)(hall + ((size_t)r1 * NN + s1) * HID + cl * 8);
        float a0 = __shfl(myq, r0) + sc0; a0 = (a0 > 0.f) ? a0 : SLOPE * a0;
        float a1 = __shfl(myq, r1) + sc1; a1 = (a1 > 0.f) ? a1 : SLOPE * a1;
        float ex0 = v0 ? __expf(a0) : 0.f;
        float ex1 = v1 ? __expf(a1) : 0.f;
        ssum += ex0 + ex1;
        #pragma unroll
        for (int u = 0; u < 8; ++u)
            acc[u] += ex0 * bf2f((ushort16)hv0[u]) + ex1 * bf2f((ushort16)hv1[u]);
    }

    #pragma unroll
    for (int o = 8; o < 64; o <<= 1) {
        ssum += __shfl_xor(ssum, o);
        #pragma unroll
        for (int u = 0; u < 8; ++u) acc[u] += __shfl_xor(acc[u], o);
    }

    if (lane < 8) {
        float inv = 1.f / fmaxf(ssum, 1e-16f);
        float o_[8];
        #pragma unroll
        for (int u = 0; u < 8; ++u) o_[u] = acc[u] * inv + bias[lane * 8 + u];
        if (do_relu) {
            #pragma unroll
            for (int u = 0; u < 8; ++u) o_[u] = fmaxf(o_[u], 0.f);
        }
        uint32 p[4];
        #pragma unroll
        for (int u = 0; u < 4; ++u)
            p[u] = (uint32)f2bf(o_[2 * u]) | ((uint32)f2bf(o_[2 * u + 1]) << 16);
        int4v pk4 = {(int)p[0], (int)p[1], (int)p[2], (int)p[3]};
        *(int4v*)(out_bf + (size_t)d * HID + lane * 8) = pk4;
    }
}

// ---------------- pooling (bf16 input; batch sorted -> run-length) ----------------
__global__ void pool_kernel(const ushort16* __restrict__ h, const int* __restrict__ batch,
                            float* __restrict__ pooled)
{
    int t = blockIdx.x * 256 + threadIdx.x;
    int c = t & 63;
    int chunk = t >> 6;
    if (chunk >= NN / 16) return;
    int n0 = chunk * 16;
    float acc = 0.f;
    int cur = batch[n0];
    for (int n = n0; n < n0 + 16; ++n) {
        int b = batch[n];
        if (b != cur) { atomicAdd(&pooled[cur * HID + c], acc); acc = 0.f; cur = b; }
        acc += bf2f(h[(size_t)n * HID + c]);
    }
    atomicAdd(&pooled[cur * HID + c], acc);
}

// ---------------- head ----------------
__global__ __launch_bounds__(256) void head_kernel(const float* __restrict__ pooled,
    const float* __restrict__ linW, const float* __restrict__ linb,
    const float* __restrict__ clfW, const float* __restrict__ clfb,
    float* __restrict__ out)
{
    __shared__ float z[NG * HID];
    __shared__ float p[NG * HID];
    int tid = threadIdx.x;
    for (int i = tid; i < NG * HID; i += 256) p[i] = pooled[i];
    __syncthreads();
    for (int idx = tid; idx < NG * HID; idx += 256) {
        int g = idx >> 6, c = idx & 63;
        float acc = linb[c];
        for (int k = 0; k < HID; ++k) acc += p[g * HID + k] * linW[k * HID + c];
        z[idx] = fmaxf(acc, 0.f);
    }
    __syncthreads();
    for (int idx = tid; idx < NG * OUTC; idx += 256) {
        int g = idx >> 5, c = idx & 31;
        float acc = clfb[c];
        for (int k = 0; k < HID; ++k) acc += z[g * HID + k] * clfW[k * OUTC + c];
        out[idx] = acc;
    }
}

// ---------------- host side ----------------
extern "C" void kernel_launch(void* const* d_in, const int* in_sizes, int n_in,
                              void* d_out, int out_size, void* d_ws, size_t ws_size,
                              hipStream_t stream)
{
    const float* x      = (const float*)d_in[0];
    const int*   eidx   = (const int*)d_in[1];
    const int*   etype  = (const int*)d_in[2];
    const int*   batch  = (const int*)d_in[3];
    const float* enc_W  = (const float*)d_in[4];
    const float* enc_b  = (const float*)d_in[5];
    const float* w0     = (const float*)d_in[6];
    const float* q0     = (const float*)d_in[7];
    const float* k0     = (const float*)d_in[8];
    const float* b0     = (const float*)d_in[9];
    const float* w1     = (const float*)d_in[10];
    const float* q1     = (const float*)d_in[11];
    const float* k1     = (const float*)d_in[12];
    const float* b1     = (const float*)d_in[13];
    const float* lin_W  = (const float*)d_in[14];
    const float* lin_b  = (const float*)d_in[15];
    const float* clf_W  = (const float*)d_in[16];
    const float* clf_b  = (const float*)d_in[17];

    const int* srcp = eidx;
    const int* dstp = eidx + NE;

    char* wsb = (char*)d_ws;
    ushort16* h_bf    = (ushort16*)wsb;                 wsb += (size_t)NN * HID * 2;
    ushort16* hall_bf = (ushort16*)wsb;                 wsb += (size_t)NREL * NN * HID * 2;
    float*    sbuf    = (float*)wsb;                    wsb += (size_t)16 * NN * 4;
    float*    wqk0    = (float*)wsb;                    wsb += 16 * HID * 4;
    float*    wqk1    = (float*)wsb;                    wsb += 16 * HID * 4;
    float*    pooled  = (float*)wsb;                    wsb += NG * HID * 4;
    int*      rowptr  = (int*)wsb;                      wsb += (size_t)(NN + 64) * 4;
    int*      bucketHist = (int*)wsb;                   wsb += 256 * 4;
    int*      bucket_cur = (int*)wsb;                   wsb += 256 * 4;
    uint32*   ebin    = (uint32*)wsb;                   wsb += (size_t)NE * 4;
    uint32*   edges_s = (uint32*)wsb;                   wsb += (size_t)(NE + 64) * 4;

    // ---- prep: wqk both layers + zero {hist, cur, pooled} ----
    prep_kernel<<<33, 256, 0, stream>>>(w0, q0, k0, w1, q1, k1, wqk0, wqk1,
                                        bucketHist, bucket_cur, pooled);

    // ---- encoder + bucket histogram (fused) ----
    enchisto_kernel<<<ENC_BLOCKS + HISTO_BLOCKS, 256, 0, stream>>>(
        x, enc_W, enc_b, h_bf, dstp, bucketHist);

    // ---- bin edges into buckets ----
    binpass<<<(NE + 4095) / 4096, 256, 0, stream>>>(srcp, dstp, etype,
                                                    bucketHist, bucket_cur, ebin);

    // ---- layer 0 (sortpass fused into sh dispatch) ----
    shsort_kernel<true><<<NB2 + S_BLOCKS + HALL_BLOCKS, 256, 0, stream>>>(
        h_bf, wqk0, w0, sbuf, hall_bf, ebin, bucketHist, rowptr, edges_s);
    agg_kernel<<<(NN + 3) / 4, 256, 0, stream>>>(rowptr, edges_s, sbuf, hall_bf, b0,
                                                 h_bf, 1);

    // ---- layer 1 (bf16 output into h_bf, feeds bf16 pool) ----
    shsort_kernel<false><<<S_BLOCKS + HALL_BLOCKS, 256, 0, stream>>>(
        h_bf, wqk1, w1, sbuf, hall_bf, ebin, bucketHist, rowptr, edges_s);
    agg_kernel<<<(NN + 3) / 4, 256, 0, stream>>>(rowptr, edges_s, sbuf, hall_bf, b1,
                                                 h_bf, 0);

    // ---- pool + head ----
    pool_kernel<<<(NN / 16 * HID + 255) / 256, 256, 0, stream>>>(h_bf, batch, pooled);
    head_kernel<<<1, 256, 0, stream>>>(pooled, lin_W, lin_b, clf_W, clf_b, (float*)d_out);
}